// Round 1
// baseline (1047.196 us; speedup 1.0000x reference)
//
#include <hip/hip_runtime.h>
#include <stdint.h>

typedef unsigned short u16;
typedef unsigned int u32;

#define NSUB 32768
#define NNZ_E 1048576

using short8 = __attribute__((ext_vector_type(8))) short;
using f32x4  = __attribute__((ext_vector_type(4))) float;

__device__ __forceinline__ u16 f2b(float f) {
  u32 u = __float_as_uint(f);
  return (u16)((u + 0x7fffu + ((u >> 16) & 1u)) >> 16);
}

// ---------------- weight f32 -> bf16 ----------------
__global__ __launch_bounds__(256) void cvt_bf16(const float* __restrict__ in,
                                                u16* __restrict__ out, int n4) {
  int i = blockIdx.x * 256 + threadIdx.x;
  if (i < n4) {
    float4 v = ((const float4*)in)[i];
    ushort4 o;
    o.x = f2b(v.x); o.y = f2b(v.y); o.z = f2b(v.z); o.w = f2b(v.w);
    ((ushort4*)out)[i] = o;
  }
}

// ---------------- gather + cast ----------------
__global__ __launch_bounds__(128) void gather_cast(const float* __restrict__ ff,
                                                   const int* __restrict__ idx,
                                                   u16* __restrict__ out) {
  int r = blockIdx.x, t = threadIdx.x;
  size_t src = (size_t)idx[r];
  float4 v = *(const float4*)(ff + src * 512 + t * 4);
  ushort4 o;
  o.x = f2b(v.x); o.y = f2b(v.y); o.z = f2b(v.z); o.w = f2b(v.w);
  *(ushort4*)(out + (size_t)r * 512 + t * 4) = o;
}

// ---------------- CSR build ----------------
__global__ __launch_bounds__(256) void edge_count(const int* __restrict__ row,
                                                  int* __restrict__ cnt) {
  int i = blockIdx.x * 256 + threadIdx.x;
  atomicAdd(&cnt[row[i]], 1);
}

__global__ __launch_bounds__(1024) void scan_rows(const int* __restrict__ cnt,
                                                  int* __restrict__ off,
                                                  int* __restrict__ cursor) {
  __shared__ int part[1024];
  int t = threadIdx.x;
  int base = t * 32;
  int sum = 0;
  for (int j = 0; j < 32; ++j) sum += cnt[base + j];
  part[t] = sum;
  __syncthreads();
  for (int d = 1; d < 1024; d <<= 1) {
    int v = part[t];
    int u = (t >= d) ? part[t - d] : 0;
    __syncthreads();
    part[t] = v + u;
    __syncthreads();
  }
  int run = part[t] - sum;  // exclusive prefix
  for (int j = 0; j < 32; ++j) {
    int c = cnt[base + j];
    off[base + j] = run;
    cursor[base + j] = run;
    run += c;
  }
  if (t == 1023) off[NSUB] = part[1023];
}

__global__ __launch_bounds__(256) void edge_scatter(const int* __restrict__ row,
                                                    const int* __restrict__ col,
                                                    const float* __restrict__ val,
                                                    int* __restrict__ cursor,
                                                    int* __restrict__ col_s,
                                                    float* __restrict__ val_s) {
  int i = blockIdx.x * 256 + threadIdx.x;
  int r = row[i];
  int p = atomicAdd(&cursor[r], 1);
  col_s[p] = col[i];
  val_s[p] = val[i];
}

// ---------------- SpMM (CSR, block per row) ----------------
template <int D>
__global__ __launch_bounds__(256) void spmm_csr(const int* __restrict__ off,
                                                const int* __restrict__ col_s,
                                                const float* __restrict__ val_s,
                                                const u16* __restrict__ X,
                                                u16* __restrict__ Y) {
  int r = blockIdx.x, t = threadIdx.x;
  int s = off[r], e = off[r + 1];
  if (D == 512) {
    float a0 = 0.f, a1 = 0.f;
    for (int i = s; i < e; ++i) {
      int c = col_s[i];
      float v = val_s[i];
      u32 u = *(const u32*)(X + (size_t)c * 512 + t * 2);
      a0 += v * __uint_as_float(u << 16);
      a1 += v * __uint_as_float(u & 0xffff0000u);
    }
    u32 o = (u32)f2b(a0) | ((u32)f2b(a1) << 16);
    *(u32*)(Y + (size_t)r * 512 + t * 2) = o;
  } else {
    float a0 = 0.f, a1 = 0.f, a2 = 0.f, a3 = 0.f;
    for (int i = s; i < e; ++i) {
      int c = col_s[i];
      float v = val_s[i];
      uint2 u = *(const uint2*)(X + (size_t)c * 1024 + t * 4);
      a0 += v * __uint_as_float(u.x << 16);
      a1 += v * __uint_as_float(u.x & 0xffff0000u);
      a2 += v * __uint_as_float(u.y << 16);
      a3 += v * __uint_as_float(u.y & 0xffff0000u);
    }
    uint2 o;
    o.x = (u32)f2b(a0) | ((u32)f2b(a1) << 16);
    o.y = (u32)f2b(a2) | ((u32)f2b(a3) << 16);
    *(uint2*)(Y + (size_t)r * 1024 + t * 4) = o;
  }
}

// ---------------- bf16 MFMA GEMM: C[M,512] = A[M,K] @ W[512,K]^T (+bias, relu) ----------------
template <int K, bool RELU>
__global__ __launch_bounds__(256) void gemm_bt(const u16* __restrict__ A,
                                               const u16* __restrict__ W,
                                               const float* __restrict__ bias,
                                               float* __restrict__ C) {
  __shared__ __align__(16) u16 As[128 * 32];
  __shared__ __align__(16) u16 Bs[128 * 32];
  const int t = threadIdx.x;
  const int lane = t & 63, wave = t >> 6;
  const int wm = (wave >> 1) * 64, wn = (wave & 1) * 64;
  const int m0 = blockIdx.y * 128, n0 = blockIdx.x * 128;

  f32x4 acc[4][4];
#pragma unroll
  for (int m = 0; m < 4; ++m)
#pragma unroll
    for (int n = 0; n < 4; ++n) acc[m][n] = f32x4{0.f, 0.f, 0.f, 0.f};

  const int lr = t >> 2;         // 0..63 (staging row)
  const int lc = (t & 3) * 8;    // 0,8,16,24 (staging col in elements)
  const u16* Ag  = A + (size_t)(m0 + lr) * K + lc;
  const u16* Ag2 = Ag + (size_t)64 * K;
  const u16* Wg  = W + (size_t)(n0 + lr) * K + lc;
  const u16* Wg2 = Wg + (size_t)64 * K;
  const int fr = lane & 15, kh = lane >> 4;

  for (int kt = 0; kt < K / 32; ++kt) {
    *(int4*)&As[lr * 32 + lc]        = *(const int4*)(Ag  + kt * 32);
    *(int4*)&As[(lr + 64) * 32 + lc] = *(const int4*)(Ag2 + kt * 32);
    *(int4*)&Bs[lr * 32 + lc]        = *(const int4*)(Wg  + kt * 32);
    *(int4*)&Bs[(lr + 64) * 32 + lc] = *(const int4*)(Wg2 + kt * 32);
    __syncthreads();
    short8 af[4], bfr[4];
#pragma unroll
    for (int m = 0; m < 4; ++m)
      af[m] = *(const short8*)&As[(wm + m * 16 + fr) * 32 + kh * 8];
#pragma unroll
    for (int n = 0; n < 4; ++n)
      bfr[n] = *(const short8*)&Bs[(wn + n * 16 + fr) * 32 + kh * 8];
#pragma unroll
    for (int m = 0; m < 4; ++m)
#pragma unroll
      for (int n = 0; n < 4; ++n)
        acc[m][n] = __builtin_amdgcn_mfma_f32_16x16x32_bf16(af[m], bfr[n], acc[m][n], 0, 0, 0);
    __syncthreads();
  }

  const int crow = (lane >> 4) * 4;  // C/D: row=(lane>>4)*4+reg, col=lane&15
  const int ccol = lane & 15;
#pragma unroll
  for (int n = 0; n < 4; ++n) {
    int col = n0 + wn + n * 16 + ccol;
    float bv = bias[col];
#pragma unroll
    for (int m = 0; m < 4; ++m) {
      int row = m0 + wm + m * 16 + crow;
#pragma unroll
      for (int q = 0; q < 4; ++q) {
        float v = acc[m][n][q] + bv;
        if (RELU) v = fmaxf(v, 0.f);
        C[(size_t)(row + q) * 512 + col] = v;
      }
    }
  }
}

// ---------------- per-row mean/var norm -> bf16 into concat buffer ----------------
__global__ __launch_bounds__(128) void rownorm(const float* __restrict__ F,
                                               const float* __restrict__ sc,
                                               const float* __restrict__ ofs,
                                               u16* __restrict__ out, int col_off) {
  int r = blockIdx.x, t = threadIdx.x;
  float4 v = *(const float4*)(F + (size_t)r * 512 + t * 4);
  float sum = v.x + v.y + v.z + v.w;
  float sq = v.x * v.x + v.y * v.y + v.z * v.z + v.w * v.w;
  for (int d = 32; d > 0; d >>= 1) {
    sum += __shfl_down(sum, d);
    sq  += __shfl_down(sq, d);
  }
  __shared__ float red[4];
  if ((t & 63) == 0) { red[(t >> 6) * 2] = sum; red[(t >> 6) * 2 + 1] = sq; }
  __syncthreads();
  float S = red[0] + red[2], Q = red[1] + red[3];
  float mean = S * (1.f / 512.f);
  float var = Q * (1.f / 512.f) - mean * mean;
  float rstd = rsqrtf(var + 1e-9f);
  float4 s4 = *(const float4*)(sc + t * 4);
  float4 o4 = *(const float4*)(ofs + t * 4);
  ushort4 o;
  o.x = f2b((v.x - mean) * s4.x * rstd + o4.x);
  o.y = f2b((v.y - mean) * s4.y * rstd + o4.y);
  o.z = f2b((v.z - mean) * s4.z * rstd + o4.z);
  o.w = f2b((v.w - mean) * s4.w * rstd + o4.w);
  *(ushort4*)(out + (size_t)r * 1024 + col_off + t * 4) = o;
}

// ---------------- per-row L2 normalize (in place, bf16 [NSUB,1024]) ----------------
__global__ __launch_bounds__(256) void l2norm(u16* __restrict__ H) {
  int r = blockIdx.x, t = threadIdx.x;
  uint2 u = *(const uint2*)(H + (size_t)r * 1024 + t * 4);
  float f0 = __uint_as_float(u.x << 16);
  float f1 = __uint_as_float(u.x & 0xffff0000u);
  float f2 = __uint_as_float(u.y << 16);
  float f3 = __uint_as_float(u.y & 0xffff0000u);
  float sq = f0 * f0 + f1 * f1 + f2 * f2 + f3 * f3;
  for (int d = 32; d > 0; d >>= 1) sq += __shfl_down(sq, d);
  __shared__ float red[4];
  if ((t & 63) == 0) red[t >> 6] = sq;
  __syncthreads();
  float S = red[0] + red[1] + red[2] + red[3];
  float inv = 1.f / fmaxf(sqrtf(S), 1e-12f);
  uint2 o;
  o.x = (u32)f2b(f0 * inv) | ((u32)f2b(f1 * inv) << 16);
  o.y = (u32)f2b(f2 * inv) | ((u32)f2b(f3 * inv) << 16);
  *(uint2*)(H + (size_t)r * 1024 + t * 4) = o;
}

extern "C" void kernel_launch(void* const* d_in, const int* in_sizes, int n_in,
                              void* d_out, int out_size, void* d_ws, size_t ws_size,
                              hipStream_t stream) {
  (void)in_sizes; (void)n_in; (void)out_size; (void)ws_size;
  const float* feat_full = (const float*)d_in[0];
  const int*   nodes = (const int*)d_in[1];
  const int*   arow = (const int*)d_in[2];
  const int*   acol = (const int*)d_in[3];
  const float* aval = (const float*)d_in[4];
  const float* W1_0 = (const float*)d_in[5];
  const float* W1_1 = (const float*)d_in[6];
  const float* b1_0 = (const float*)d_in[7];
  const float* b1_1 = (const float*)d_in[8];
  const float* s1_0 = (const float*)d_in[9];
  const float* s1_1 = (const float*)d_in[10];
  const float* o1_0 = (const float*)d_in[11];
  const float* o1_1 = (const float*)d_in[12];
  const float* W2_0 = (const float*)d_in[13];
  const float* W2_1 = (const float*)d_in[14];
  const float* b2_0 = (const float*)d_in[15];
  const float* b2_1 = (const float*)d_in[16];
  const float* s2_0 = (const float*)d_in[17];
  const float* s2_1 = (const float*)d_in[18];
  const float* o2_0 = (const float*)d_in[19];
  const float* o2_1 = (const float*)d_in[20];
  const float* Wc = (const float*)d_in[21];
  const float* bc = (const float*)d_in[22];
  float* out = (float*)d_out;

  const size_t MB = (size_t)1 << 20;
  char* p = (char*)d_ws;
  u16* FEAT = (u16*)p;                    // 32 MiB [NSUB,512] bf16
  u16* S1   = (u16*)(p + 32 * MB);        // 32 MiB
  u16* S2   = (u16*)p;                    // reuses FEAT+S1 region (64 MiB) in layer 2
  u16* H1   = (u16*)(p + 64 * MB);        // 64 MiB [NSUB,1024]
  u16* H2   = (u16*)(p + 128 * MB);       // 64 MiB
  float* TMP = (float*)(p + 192 * MB);    // 64 MiB f32 [NSUB,512]
  u16* W1_0b = (u16*)(p + 256 * MB);
  u16* W1_1b = W1_0b + 512 * 512;
  u16* W2_0b = W1_1b + 512 * 512;
  u16* W2_1b = W2_0b + 512 * 1024;
  u16* Wcb   = W2_1b + 512 * 1024;
  int* row_off = (int*)(p + 264 * MB);    // 32769 ints (reserve 33024)
  int* cnt    = row_off + 33024;
  int* cursor = cnt + NSUB;
  int* col_s  = cursor + NSUB;
  float* val_s = (float*)(col_s + NNZ_E);

  hipMemsetAsync(cnt, 0, NSUB * sizeof(int), stream);

  // weights -> bf16
  cvt_bf16<<<(512 * 512 / 4 + 255) / 256, 256, 0, stream>>>(W1_0, W1_0b, 512 * 512 / 4);
  cvt_bf16<<<(512 * 512 / 4 + 255) / 256, 256, 0, stream>>>(W1_1, W1_1b, 512 * 512 / 4);
  cvt_bf16<<<(512 * 1024 / 4 + 255) / 256, 256, 0, stream>>>(W2_0, W2_0b, 512 * 1024 / 4);
  cvt_bf16<<<(512 * 1024 / 4 + 255) / 256, 256, 0, stream>>>(W2_1, W2_1b, 512 * 1024 / 4);
  cvt_bf16<<<(512 * 1024 / 4 + 255) / 256, 256, 0, stream>>>(Wc, Wcb, 512 * 1024 / 4);

  gather_cast<<<NSUB, 128, 0, stream>>>(feat_full, nodes, FEAT);

  // CSR build
  edge_count<<<NNZ_E / 256, 256, 0, stream>>>(arow, cnt);
  scan_rows<<<1, 1024, 0, stream>>>(cnt, row_off, cursor);
  edge_scatter<<<NNZ_E / 256, 256, 0, stream>>>(arow, acol, aval, cursor, col_s, val_s);

  // layer 1
  spmm_csr<512><<<NSUB, 256, 0, stream>>>(row_off, col_s, val_s, FEAT, S1);
  gemm_bt<512, true><<<dim3(4, 256), 256, 0, stream>>>(FEAT, W1_0b, b1_0, TMP);
  rownorm<<<NSUB, 128, 0, stream>>>(TMP, s1_0, o1_0, H1, 0);
  gemm_bt<512, true><<<dim3(4, 256), 256, 0, stream>>>(S1, W1_1b, b1_1, TMP);
  rownorm<<<NSUB, 128, 0, stream>>>(TMP, s1_1, o1_1, H1, 512);

  // layer 2
  spmm_csr<1024><<<NSUB, 256, 0, stream>>>(row_off, col_s, val_s, H1, S2);
  gemm_bt<1024, true><<<dim3(4, 256), 256, 0, stream>>>(H1, W2_0b, b2_0, TMP);
  rownorm<<<NSUB, 128, 0, stream>>>(TMP, s2_0, o2_0, H2, 0);
  gemm_bt<1024, true><<<dim3(4, 256), 256, 0, stream>>>(S2, W2_1b, b2_1, TMP);
  rownorm<<<NSUB, 128, 0, stream>>>(TMP, s2_1, o2_1, H2, 512);

  // L2 normalize + classifier
  l2norm<<<NSUB, 256, 0, stream>>>(H2);
  gemm_bt<1024, false><<<dim3(4, 256), 256, 0, stream>>>(H2, Wcb, bc, out);
}

// Round 2
// 834.131 us; speedup vs baseline: 1.2554x; 1.2554x over previous
//
#include <hip/hip_runtime.h>
#include <stdint.h>

typedef unsigned short u16;
typedef unsigned int u32;

#define NSUB 32768
#define NNZ_E 1048576

using short8 = __attribute__((ext_vector_type(8))) short;
using f32x4  = __attribute__((ext_vector_type(4))) float;

__device__ __forceinline__ u16 f2b(float f) {
  u32 u = __float_as_uint(f);
  return (u16)((u + 0x7fffu + ((u >> 16) & 1u)) >> 16);
}

__device__ __forceinline__ void glds16(const void* g, void* l) {
  __builtin_amdgcn_global_load_lds(
      (const __attribute__((address_space(1))) u32*)g,
      (__attribute__((address_space(3))) u32*)l, 16, 0, 0);
}

// ---------------- weight f32 -> bf16 ----------------
__global__ __launch_bounds__(256) void cvt_bf16(const float* __restrict__ in,
                                                u16* __restrict__ out, int n4) {
  int i = blockIdx.x * 256 + threadIdx.x;
  if (i < n4) {
    float4 v = ((const float4*)in)[i];
    ushort4 o;
    o.x = f2b(v.x); o.y = f2b(v.y); o.z = f2b(v.z); o.w = f2b(v.w);
    ((ushort4*)out)[i] = o;
  }
}

// ---------------- gather + cast ----------------
__global__ __launch_bounds__(128) void gather_cast(const float* __restrict__ ff,
                                                   const int* __restrict__ idx,
                                                   u16* __restrict__ out) {
  int r = blockIdx.x, t = threadIdx.x;
  size_t src = (size_t)idx[r];
  float4 v = *(const float4*)(ff + src * 512 + t * 4);
  ushort4 o;
  o.x = f2b(v.x); o.y = f2b(v.y); o.z = f2b(v.z); o.w = f2b(v.w);
  *(ushort4*)(out + (size_t)r * 512 + t * 4) = o;
}

// ---------------- CSR build ----------------
__global__ __launch_bounds__(256) void edge_count(const int* __restrict__ row,
                                                  int* __restrict__ cnt) {
  int i = blockIdx.x * 256 + threadIdx.x;
  atomicAdd(&cnt[row[i]], 1);
}

__global__ __launch_bounds__(1024) void scan_rows(const int* __restrict__ cnt,
                                                  int* __restrict__ off,
                                                  int* __restrict__ cursor) {
  __shared__ int part[1024];
  int t = threadIdx.x;
  int base = t * 32;
  int sum = 0;
  for (int j = 0; j < 32; ++j) sum += cnt[base + j];
  part[t] = sum;
  __syncthreads();
  for (int d = 1; d < 1024; d <<= 1) {
    int v = part[t];
    int u = (t >= d) ? part[t - d] : 0;
    __syncthreads();
    part[t] = v + u;
    __syncthreads();
  }
  int run = part[t] - sum;  // exclusive prefix
  for (int j = 0; j < 32; ++j) {
    int c = cnt[base + j];
    off[base + j] = run;
    cursor[base + j] = run;
    run += c;
  }
  if (t == 1023) off[NSUB] = part[1023];
}

__global__ __launch_bounds__(256) void edge_scatter(const int* __restrict__ row,
                                                    const int* __restrict__ col,
                                                    const float* __restrict__ val,
                                                    int* __restrict__ cursor,
                                                    int* __restrict__ col_s,
                                                    float* __restrict__ val_s) {
  int i = blockIdx.x * 256 + threadIdx.x;
  int r = row[i];
  int p = atomicAdd(&cursor[r], 1);
  col_s[p] = col[i];
  val_s[p] = val[i];
}

// ---------------- SpMM D=512, one wave per row, 16B gathers ----------------
__device__ __forceinline__ void fma8(int4 u, float v, float* a) {
  u32 w;
  w = (u32)u.x; a[0] += v * __uint_as_float(w << 16); a[1] += v * __uint_as_float(w & 0xffff0000u);
  w = (u32)u.y; a[2] += v * __uint_as_float(w << 16); a[3] += v * __uint_as_float(w & 0xffff0000u);
  w = (u32)u.z; a[4] += v * __uint_as_float(w << 16); a[5] += v * __uint_as_float(w & 0xffff0000u);
  w = (u32)u.w; a[6] += v * __uint_as_float(w << 16); a[7] += v * __uint_as_float(w & 0xffff0000u);
}

template <bool F32OUT>
__global__ __launch_bounds__(256) void spmm512(const int* __restrict__ off,
                                               const int* __restrict__ col_s,
                                               const float* __restrict__ val_s,
                                               const u16* __restrict__ X,
                                               u16* __restrict__ Yb,
                                               float* __restrict__ Yf) {
  const int lane = threadIdx.x & 63, wave = threadIdx.x >> 6;
  const int r = blockIdx.x * 4 + wave;
  const int s = __builtin_amdgcn_readfirstlane(off[r]);
  const int e = __builtin_amdgcn_readfirstlane(off[r + 1]);
  float a[8] = {0.f, 0.f, 0.f, 0.f, 0.f, 0.f, 0.f, 0.f};
  const u16* Xl = X + lane * 8;
  int i = s;
  for (; i + 2 <= e; i += 2) {
    int c0 = col_s[i], c1 = col_s[i + 1];
    float v0 = val_s[i], v1 = val_s[i + 1];
    int4 u0 = *(const int4*)(Xl + (size_t)c0 * 512);
    int4 u1 = *(const int4*)(Xl + (size_t)c1 * 512);
    fma8(u0, v0, a);
    fma8(u1, v1, a);
  }
  if (i < e) {
    int c0 = col_s[i];
    float v0 = val_s[i];
    int4 u0 = *(const int4*)(Xl + (size_t)c0 * 512);
    fma8(u0, v0, a);
  }
  if (F32OUT) {
    float4 o0 = {a[0], a[1], a[2], a[3]}, o1 = {a[4], a[5], a[6], a[7]};
    *(float4*)(Yf + (size_t)r * 512 + lane * 8) = o0;
    *(float4*)(Yf + (size_t)r * 512 + lane * 8 + 4) = o1;
  } else {
    int4 o;
    o.x = (int)((u32)f2b(a[0]) | ((u32)f2b(a[1]) << 16));
    o.y = (int)((u32)f2b(a[2]) | ((u32)f2b(a[3]) << 16));
    o.z = (int)((u32)f2b(a[4]) | ((u32)f2b(a[5]) << 16));
    o.w = (int)((u32)f2b(a[6]) | ((u32)f2b(a[7]) << 16));
    *(int4*)(Yb + (size_t)r * 512 + lane * 8) = o;
  }
}

// ---------------- bf16 MFMA GEMM: C[M,512] = A[M,K] @ W[512,K]^T ----------------
// glds-staged, 128x128 tile. BIAS: add bias[col] (classifier). BF16OUT: write bf16.
template <int K, bool BIAS, bool BF16OUT>
__global__ __launch_bounds__(256) void gemm_bt(const u16* __restrict__ A,
                                               const u16* __restrict__ W,
                                               const float* __restrict__ bias,
                                               float* __restrict__ Cf,
                                               u16* __restrict__ Cb) {
  __shared__ __align__(16) u16 As[128 * 32];
  __shared__ __align__(16) u16 Bs[128 * 32];
  const int t = threadIdx.x;
  const int lane = t & 63, wave = t >> 6;
  const int wm = (wave >> 1) * 64, wn = (wave & 1) * 64;
  const int m0 = blockIdx.y * 128, n0 = blockIdx.x * 128;

  f32x4 acc[4][4];
#pragma unroll
  for (int m = 0; m < 4; ++m)
#pragma unroll
    for (int n = 0; n < 4; ++n) acc[m][n] = f32x4{0.f, 0.f, 0.f, 0.f};

  const int lr = t >> 2;       // 0..63
  const int lc = (t & 3) * 8;  // elements
  const u16* Ag  = A + (size_t)(m0 + lr) * K + lc;
  const u16* Ag2 = Ag + (size_t)64 * K;
  const u16* Wg  = W + (size_t)(n0 + lr) * K + lc;
  const u16* Wg2 = Wg + (size_t)64 * K;
  char* asb0 = (char*)As + wave * 1024;
  char* asb1 = (char*)As + 4096 + wave * 1024;
  char* bsb0 = (char*)Bs + wave * 1024;
  char* bsb1 = (char*)Bs + 4096 + wave * 1024;
  const int fr = lane & 15, kh = lane >> 4;

  for (int kt = 0; kt < K / 32; ++kt) {
    glds16(Ag + kt * 32, asb0);
    glds16(Ag2 + kt * 32, asb1);
    glds16(Wg + kt * 32, bsb0);
    glds16(Wg2 + kt * 32, bsb1);
    __syncthreads();
    short8 af[4], bfr[4];
#pragma unroll
    for (int m = 0; m < 4; ++m)
      af[m] = *(const short8*)&As[(wm + m * 16 + fr) * 32 + kh * 8];
#pragma unroll
    for (int n = 0; n < 4; ++n)
      bfr[n] = *(const short8*)&Bs[(wn + n * 16 + fr) * 32 + kh * 8];
#pragma unroll
    for (int m = 0; m < 4; ++m)
#pragma unroll
      for (int n = 0; n < 4; ++n)
        acc[m][n] = __builtin_amdgcn_mfma_f32_16x16x32_bf16(af[m], bfr[n], acc[m][n], 0, 0, 0);
    __syncthreads();
  }

  const int crow = (lane >> 4) * 4;  // C/D: row=(lane>>4)*4+reg, col=lane&15
  const int ccol = lane & 15;
#pragma unroll
  for (int n = 0; n < 4; ++n) {
    int col = n0 + wn + n * 16 + ccol;
    float bv = BIAS ? bias[col] : 0.f;
#pragma unroll
    for (int m = 0; m < 4; ++m) {
      int row = m0 + wm + m * 16 + crow;
#pragma unroll
      for (int q = 0; q < 4; ++q) {
        float v = acc[m][n][q] + bv;
        if (BF16OUT)
          Cb[(size_t)(row + q) * 512 + col] = f2b(v);
        else
          Cf[(size_t)(row + q) * 512 + col] = v;
      }
    }
  }
}

// ---------------- fused bias + relu + per-row mean/var norm -> bf16 ----------------
__global__ __launch_bounds__(128) void rownorm(const float* __restrict__ F,
                                               const float* __restrict__ bias,
                                               const float* __restrict__ sc,
                                               const float* __restrict__ ofs,
                                               u16* __restrict__ out, int col_off) {
  int r = blockIdx.x, t = threadIdx.x;
  float4 v = *(const float4*)(F + (size_t)r * 512 + t * 4);
  float4 b4 = *(const float4*)(bias + t * 4);
  v.x = fmaxf(v.x + b4.x, 0.f);
  v.y = fmaxf(v.y + b4.y, 0.f);
  v.z = fmaxf(v.z + b4.z, 0.f);
  v.w = fmaxf(v.w + b4.w, 0.f);
  float sum = v.x + v.y + v.z + v.w;
  float sq = v.x * v.x + v.y * v.y + v.z * v.z + v.w * v.w;
  for (int d = 32; d > 0; d >>= 1) {
    sum += __shfl_down(sum, d);
    sq  += __shfl_down(sq, d);
  }
  __shared__ float red[4];
  if ((t & 63) == 0) { red[(t >> 6) * 2] = sum; red[(t >> 6) * 2 + 1] = sq; }
  __syncthreads();
  float S = red[0] + red[2], Q = red[1] + red[3];
  float mean = S * (1.f / 512.f);
  float var = Q * (1.f / 512.f) - mean * mean;
  float rstd = rsqrtf(var + 1e-9f);
  float4 s4 = *(const float4*)(sc + t * 4);
  float4 o4 = *(const float4*)(ofs + t * 4);
  ushort4 o;
  o.x = f2b((v.x - mean) * s4.x * rstd + o4.x);
  o.y = f2b((v.y - mean) * s4.y * rstd + o4.y);
  o.z = f2b((v.z - mean) * s4.z * rstd + o4.z);
  o.w = f2b((v.w - mean) * s4.w * rstd + o4.w);
  *(ushort4*)(out + (size_t)r * 1024 + col_off + t * 4) = o;
}

// ---------------- per-row L2 normalize (in place, bf16 [NSUB,1024]) ----------------
__global__ __launch_bounds__(256) void l2norm(u16* __restrict__ H) {
  int r = blockIdx.x, t = threadIdx.x;
  uint2 u = *(const uint2*)(H + (size_t)r * 1024 + t * 4);
  float f0 = __uint_as_float(u.x << 16);
  float f1 = __uint_as_float(u.x & 0xffff0000u);
  float f2 = __uint_as_float(u.y << 16);
  float f3 = __uint_as_float(u.y & 0xffff0000u);
  float sq = f0 * f0 + f1 * f1 + f2 * f2 + f3 * f3;
  for (int d = 32; d > 0; d >>= 1) sq += __shfl_down(sq, d);
  __shared__ float red[4];
  if ((t & 63) == 0) red[t >> 6] = sq;
  __syncthreads();
  float S = red[0] + red[1] + red[2] + red[3];
  float inv = 1.f / fmaxf(sqrtf(S), 1e-12f);
  uint2 o;
  o.x = (u32)f2b(f0 * inv) | ((u32)f2b(f1 * inv) << 16);
  o.y = (u32)f2b(f2 * inv) | ((u32)f2b(f3 * inv) << 16);
  *(uint2*)(H + (size_t)r * 1024 + t * 4) = o;
}

extern "C" void kernel_launch(void* const* d_in, const int* in_sizes, int n_in,
                              void* d_out, int out_size, void* d_ws, size_t ws_size,
                              hipStream_t stream) {
  (void)in_sizes; (void)n_in; (void)out_size; (void)ws_size;
  const float* feat_full = (const float*)d_in[0];
  const int*   nodes = (const int*)d_in[1];
  const int*   arow = (const int*)d_in[2];
  const int*   acol = (const int*)d_in[3];
  const float* aval = (const float*)d_in[4];
  const float* W1_0 = (const float*)d_in[5];
  const float* W1_1 = (const float*)d_in[6];
  const float* b1_0 = (const float*)d_in[7];
  const float* b1_1 = (const float*)d_in[8];
  const float* s1_0 = (const float*)d_in[9];
  const float* s1_1 = (const float*)d_in[10];
  const float* o1_0 = (const float*)d_in[11];
  const float* o1_1 = (const float*)d_in[12];
  const float* W2_0 = (const float*)d_in[13];
  const float* W2_1 = (const float*)d_in[14];
  const float* b2_0 = (const float*)d_in[15];
  const float* b2_1 = (const float*)d_in[16];
  const float* s2_0 = (const float*)d_in[17];
  const float* s2_1 = (const float*)d_in[18];
  const float* o2_0 = (const float*)d_in[19];
  const float* o2_1 = (const float*)d_in[20];
  const float* Wc = (const float*)d_in[21];
  const float* bc = (const float*)d_in[22];
  float* out = (float*)d_out;

  const size_t MB = (size_t)1 << 20;
  char* p = (char*)d_ws;
  u16* FEAT = (u16*)p;                    // 32 MiB [NSUB,512] bf16
  u16* G2   = (u16*)p;                    // reuses FEAT (dead after layer-1 gemms)
  u16* S1   = (u16*)(p + 32 * MB);        // 32 MiB
  u16* H1   = (u16*)(p + 64 * MB);        // 64 MiB [NSUB,1024]
  u16* H2   = (u16*)(p + 128 * MB);       // 64 MiB
  float* TMP = (float*)(p + 192 * MB);    // 64 MiB f32 [NSUB,512]
  u16* W1_0b = (u16*)(p + 256 * MB);
  u16* W1_1b = W1_0b + 512 * 512;
  u16* W2_0b = W1_1b + 512 * 512;
  u16* W2_1b = W2_0b + 512 * 1024;
  u16* Wcb   = W2_1b + 512 * 1024;
  int* row_off = (int*)(p + 264 * MB);
  int* cnt    = row_off + 33024;
  int* cursor = cnt + NSUB;
  int* col_s  = cursor + NSUB;
  float* val_s = (float*)(col_s + NNZ_E);

  hipMemsetAsync(cnt, 0, NSUB * sizeof(int), stream);

  // weights -> bf16
  cvt_bf16<<<(512 * 512 / 4 + 255) / 256, 256, 0, stream>>>(W1_0, W1_0b, 512 * 512 / 4);
  cvt_bf16<<<(512 * 512 / 4 + 255) / 256, 256, 0, stream>>>(W1_1, W1_1b, 512 * 512 / 4);
  cvt_bf16<<<(512 * 1024 / 4 + 255) / 256, 256, 0, stream>>>(W2_0, W2_0b, 512 * 1024 / 4);
  cvt_bf16<<<(512 * 1024 / 4 + 255) / 256, 256, 0, stream>>>(W2_1, W2_1b, 512 * 1024 / 4);
  cvt_bf16<<<(512 * 1024 / 4 + 255) / 256, 256, 0, stream>>>(Wc, Wcb, 512 * 1024 / 4);

  gather_cast<<<NSUB, 128, 0, stream>>>(feat_full, nodes, FEAT);

  // CSR build
  edge_count<<<NNZ_E / 256, 256, 0, stream>>>(arow, cnt);
  scan_rows<<<1, 1024, 0, stream>>>(cnt, row_off, cursor);
  edge_scatter<<<NNZ_E / 256, 256, 0, stream>>>(arow, acol, aval, cursor, col_s, val_s);

  // ---- layer 1 ----
  // S1 = A @ FEAT (bf16)
  spmm512<false><<<NSUB / 4, 256, 0, stream>>>(row_off, col_s, val_s, FEAT, S1, nullptr);
  // hop0: TMP = FEAT @ W1_0^T ; rownorm(+b1_0, relu) -> H1[:, :512]
  gemm_bt<512, false, false><<<dim3(4, 256), 256, 0, stream>>>(FEAT, W1_0b, nullptr, TMP, nullptr);
  rownorm<<<NSUB, 128, 0, stream>>>(TMP, b1_0, s1_0, o1_0, H1, 0);
  // hop1: TMP = S1 @ W1_1^T ; rownorm(+b1_1, relu) -> H1[:, 512:]
  gemm_bt<512, false, false><<<dim3(4, 256), 256, 0, stream>>>(S1, W1_1b, nullptr, TMP, nullptr);
  rownorm<<<NSUB, 128, 0, stream>>>(TMP, b1_1, s1_1, o1_1, H1, 512);

  // ---- layer 2 (reordered: GEMM before SpMM for hop1) ----
  // hop0: TMP = H1 @ W2_0^T ; rownorm(+b2_0, relu) -> H2[:, :512]
  gemm_bt<1024, false, false><<<dim3(4, 256), 256, 0, stream>>>(H1, W2_0b, nullptr, TMP, nullptr);
  rownorm<<<NSUB, 128, 0, stream>>>(TMP, b2_0, s2_0, o2_0, H2, 0);
  // hop1: G2 = H1 @ W2_1^T (bf16), TMP = A @ G2 (f32), rownorm -> H2[:, 512:]
  gemm_bt<1024, false, true><<<dim3(4, 256), 256, 0, stream>>>(H1, W2_1b, nullptr, nullptr, G2);
  spmm512<true><<<NSUB / 4, 256, 0, stream>>>(row_off, col_s, val_s, G2, nullptr, TMP);
  rownorm<<<NSUB, 128, 0, stream>>>(TMP, b2_1, s2_1, o2_1, H2, 512);

  // ---- L2 normalize + classifier ----
  l2norm<<<NSUB, 256, 0, stream>>>(H2);
  gemm_bt<1024, true, false><<<dim3(4, 256), 256, 0, stream>>>(H2, Wcb, bc, out, nullptr);
}

// Round 5
// 725.302 us; speedup vs baseline: 1.4438x; 1.1500x over previous
//
#include <hip/hip_runtime.h>
#include <stdint.h>

typedef unsigned short u16;
typedef unsigned int u32;

#define NSUB 32768
#define NNZ_E 1048576

using short8 = __attribute__((ext_vector_type(8))) short;
using f32x4  = __attribute__((ext_vector_type(4))) float;

__device__ __forceinline__ u16 f2b(float f) {
  u32 u = __float_as_uint(f);
  return (u16)((u + 0x7fffu + ((u >> 16) & 1u)) >> 16);
}
__device__ __forceinline__ float b2f(u16 x) {
  return __uint_as_float(((u32)x) << 16);
}

__device__ __forceinline__ void glds16(const void* g, void* l) {
  __builtin_amdgcn_global_load_lds(
      (const __attribute__((address_space(1))) u32*)g,
      (__attribute__((address_space(3))) u32*)l, 16, 0, 0);
}

// ---------------- weight f32 -> bf16 ----------------
__global__ __launch_bounds__(256) void cvt_bf16(const float* __restrict__ in,
                                                u16* __restrict__ out, int n4) {
  int i = blockIdx.x * 256 + threadIdx.x;
  if (i < n4) {
    float4 v = ((const float4*)in)[i];
    ushort4 o;
    o.x = f2b(v.x); o.y = f2b(v.y); o.z = f2b(v.z); o.w = f2b(v.w);
    ((ushort4*)out)[i] = o;
  }
}

// ---------------- gather + cast ----------------
__global__ __launch_bounds__(128) void gather_cast(const float* __restrict__ ff,
                                                   const int* __restrict__ idx,
                                                   u16* __restrict__ out) {
  int r = blockIdx.x, t = threadIdx.x;
  size_t src = (size_t)idx[r];
  float4 v = *(const float4*)(ff + src * 512 + t * 4);
  ushort4 o;
  o.x = f2b(v.x); o.y = f2b(v.y); o.z = f2b(v.z); o.w = f2b(v.w);
  *(ushort4*)(out + (size_t)r * 512 + t * 4) = o;
}

// ---------------- CSR build ----------------
__global__ __launch_bounds__(256) void edge_count(const int* __restrict__ row,
                                                  int* __restrict__ cnt) {
  int i = blockIdx.x * 256 + threadIdx.x;
  atomicAdd(&cnt[row[i]], 1);
}

__global__ __launch_bounds__(1024) void scan_rows(const int* __restrict__ cnt,
                                                  int* __restrict__ off,
                                                  int* __restrict__ cursor) {
  __shared__ int part[1024];
  int t = threadIdx.x;
  int base = t * 32;
  int sum = 0;
  for (int j = 0; j < 32; ++j) sum += cnt[base + j];
  part[t] = sum;
  __syncthreads();
  for (int d = 1; d < 1024; d <<= 1) {
    int v = part[t];
    int u = (t >= d) ? part[t - d] : 0;
    __syncthreads();
    part[t] = v + u;
    __syncthreads();
  }
  int run = part[t] - sum;  // exclusive prefix
  for (int j = 0; j < 32; ++j) {
    int c = cnt[base + j];
    off[base + j] = run;
    cursor[base + j] = run;
    run += c;
  }
  if (t == 1023) off[NSUB] = part[1023];
}

__global__ __launch_bounds__(256) void edge_scatter(const int* __restrict__ row,
                                                    const int* __restrict__ col,
                                                    const float* __restrict__ val,
                                                    int* __restrict__ cursor,
                                                    int2* __restrict__ cv) {
  int i = blockIdx.x * 256 + threadIdx.x;
  int r = row[i];
  int p = atomicAdd(&cursor[r], 1);
  int2 e; e.x = col[i]; e.y = __float_as_int(val[i]);
  cv[p] = e;
}

// ---------------- SpMM, one wave per row, 16B gathers, MLP=4 ----------------
__device__ __forceinline__ void fma8(int4 u, float v, float* a) {
  u32 w;
  w = (u32)u.x; a[0] += v * __uint_as_float(w << 16); a[1] += v * __uint_as_float(w & 0xffff0000u);
  w = (u32)u.y; a[2] += v * __uint_as_float(w << 16); a[3] += v * __uint_as_float(w & 0xffff0000u);
  w = (u32)u.z; a[4] += v * __uint_as_float(w << 16); a[5] += v * __uint_as_float(w & 0xffff0000u);
  w = (u32)u.w; a[6] += v * __uint_as_float(w << 16); a[7] += v * __uint_as_float(w & 0xffff0000u);
}

// NORM=false: Y[r*ldy + lane*8..] = bf16(acc)  (plain aggregated features)
// NORM=true : fused bias+relu+mean/var-norm -> bf16
template <int LDX, bool NORM>
__global__ __launch_bounds__(256) void spmm512(const int* __restrict__ off,
                                               const int2* __restrict__ cv,
                                               const u16* __restrict__ X,
                                               u16* __restrict__ Y, int ldy,
                                               const float* __restrict__ bias,
                                               const float* __restrict__ sc,
                                               const float* __restrict__ ofs) {
  const int lane = threadIdx.x & 63, wave = threadIdx.x >> 6;
  const int r = blockIdx.x * 4 + wave;
  const int s = __builtin_amdgcn_readfirstlane(off[r]);
  const int e = __builtin_amdgcn_readfirstlane(off[r + 1]);
  float a[8] = {0.f, 0.f, 0.f, 0.f, 0.f, 0.f, 0.f, 0.f};
  const u16* Xl = X + lane * 8;
  int i = s;
  for (; i + 4 <= e; i += 4) {
    int2 p0 = cv[i], p1 = cv[i + 1], p2 = cv[i + 2], p3 = cv[i + 3];
    int4 u0 = *(const int4*)(Xl + (size_t)p0.x * LDX);
    int4 u1 = *(const int4*)(Xl + (size_t)p1.x * LDX);
    int4 u2 = *(const int4*)(Xl + (size_t)p2.x * LDX);
    int4 u3 = *(const int4*)(Xl + (size_t)p3.x * LDX);
    fma8(u0, __int_as_float(p0.y), a);
    fma8(u1, __int_as_float(p1.y), a);
    fma8(u2, __int_as_float(p2.y), a);
    fma8(u3, __int_as_float(p3.y), a);
  }
  for (; i < e; ++i) {
    int2 p0 = cv[i];
    int4 u0 = *(const int4*)(Xl + (size_t)p0.x * LDX);
    fma8(u0, __int_as_float(p0.y), a);
  }
  if (NORM) {
    float4 b0 = *(const float4*)(bias + lane * 8);
    float4 b1 = *(const float4*)(bias + lane * 8 + 4);
    a[0] = fmaxf(a[0] + b0.x, 0.f); a[1] = fmaxf(a[1] + b0.y, 0.f);
    a[2] = fmaxf(a[2] + b0.z, 0.f); a[3] = fmaxf(a[3] + b0.w, 0.f);
    a[4] = fmaxf(a[4] + b1.x, 0.f); a[5] = fmaxf(a[5] + b1.y, 0.f);
    a[6] = fmaxf(a[6] + b1.z, 0.f); a[7] = fmaxf(a[7] + b1.w, 0.f);
    float sum = 0.f, sq = 0.f;
#pragma unroll
    for (int j = 0; j < 8; ++j) { sum += a[j]; sq += a[j] * a[j]; }
#pragma unroll
    for (int d = 1; d < 64; d <<= 1) {
      sum += __shfl_xor(sum, d);
      sq  += __shfl_xor(sq, d);
    }
    float mean = sum * (1.f / 512.f);
    float var = sq * (1.f / 512.f) - mean * mean;
    float rstd = rsqrtf(var + 1e-9f);
    float4 s0 = *(const float4*)(sc + lane * 8);
    float4 s1 = *(const float4*)(sc + lane * 8 + 4);
    float4 o0 = *(const float4*)(ofs + lane * 8);
    float4 o1 = *(const float4*)(ofs + lane * 8 + 4);
    int4 o;
    o.x = (int)((u32)f2b((a[0] - mean) * s0.x * rstd + o0.x) |
                ((u32)f2b((a[1] - mean) * s0.y * rstd + o0.y) << 16));
    o.y = (int)((u32)f2b((a[2] - mean) * s0.z * rstd + o0.z) |
                ((u32)f2b((a[3] - mean) * s0.w * rstd + o0.w) << 16));
    o.z = (int)((u32)f2b((a[4] - mean) * s1.x * rstd + o1.x) |
                ((u32)f2b((a[5] - mean) * s1.y * rstd + o1.y) << 16));
    o.w = (int)((u32)f2b((a[6] - mean) * s1.z * rstd + o1.z) |
                ((u32)f2b((a[7] - mean) * s1.w * rstd + o1.w) << 16));
    *(int4*)(Y + (size_t)r * ldy + lane * 8) = o;
  } else {
    int4 o;
    o.x = (int)((u32)f2b(a[0]) | ((u32)f2b(a[1]) << 16));
    o.y = (int)((u32)f2b(a[2]) | ((u32)f2b(a[3]) << 16));
    o.z = (int)((u32)f2b(a[4]) | ((u32)f2b(a[5]) << 16));
    o.w = (int)((u32)f2b(a[6]) | ((u32)f2b(a[7]) << 16));
    *(int4*)(Y + (size_t)r * ldy + lane * 8) = o;
  }
}

// ---------------- bf16 MFMA GEMM: C[M,N] = A[M,K] @ W[N,K]^T ----------------
// 128x128 tile, glds staging, XCD-aware block swizzle.
template <int K, int LDC, bool BIAS, bool BF16OUT>
__global__ __launch_bounds__(256) void gemm_bt(const u16* __restrict__ A,
                                               const u16* __restrict__ W,
                                               const float* __restrict__ bias,
                                               float* __restrict__ Cf,
                                               u16* __restrict__ Cb) {
  __shared__ __align__(16) u16 As[128 * 32];
  __shared__ __align__(16) u16 Bs[128 * 32];
  const int t = threadIdx.x;
  const int lane = t & 63, wave = t >> 6;
  const int wm = (wave >> 1) * 64, wn = (wave & 1) * 64;
  // XCD swizzle (grid size divisible by 8): colocate N-tiles sharing an A panel
  const int nwg = gridDim.x * gridDim.y;
  const int bid = blockIdx.x + gridDim.x * blockIdx.y;
  const int sbid = (bid % 8) * (nwg / 8) + bid / 8;
  const int bx = sbid % gridDim.x, by = sbid / gridDim.x;
  const int m0 = by * 128, n0 = bx * 128;

  f32x4 acc[4][4];
#pragma unroll
  for (int m = 0; m < 4; ++m)
#pragma unroll
    for (int n = 0; n < 4; ++n) acc[m][n] = f32x4{0.f, 0.f, 0.f, 0.f};

  const int lr = t >> 2;       // 0..63
  const int lc = (t & 3) * 8;  // elements
  const u16* Ag  = A + (size_t)(m0 + lr) * K + lc;
  const u16* Ag2 = Ag + (size_t)64 * K;
  const u16* Wg  = W + (size_t)(n0 + lr) * K + lc;
  const u16* Wg2 = Wg + (size_t)64 * K;
  char* asb0 = (char*)As + wave * 1024;
  char* asb1 = (char*)As + 4096 + wave * 1024;
  char* bsb0 = (char*)Bs + wave * 1024;
  char* bsb1 = (char*)Bs + 4096 + wave * 1024;
  const int fr = lane & 15, kh = lane >> 4;

  for (int kt = 0; kt < K / 32; ++kt) {
    glds16(Ag + kt * 32, asb0);
    glds16(Ag2 + kt * 32, asb1);
    glds16(Wg + kt * 32, bsb0);
    glds16(Wg2 + kt * 32, bsb1);
    __syncthreads();
    short8 af[4], bfr[4];
#pragma unroll
    for (int m = 0; m < 4; ++m)
      af[m] = *(const short8*)&As[(wm + m * 16 + fr) * 32 + kh * 8];
#pragma unroll
    for (int n = 0; n < 4; ++n)
      bfr[n] = *(const short8*)&Bs[(wn + n * 16 + fr) * 32 + kh * 8];
#pragma unroll
    for (int m = 0; m < 4; ++m)
#pragma unroll
      for (int n = 0; n < 4; ++n)
        acc[m][n] = __builtin_amdgcn_mfma_f32_16x16x32_bf16(af[m], bfr[n], acc[m][n], 0, 0, 0);
    __syncthreads();
  }

  const int crow = (lane >> 4) * 4;  // C/D: row=(lane>>4)*4+reg, col=lane&15
  const int ccol = lane & 15;
#pragma unroll
  for (int n = 0; n < 4; ++n) {
    int col = n0 + wn + n * 16 + ccol;
    float bv = BIAS ? bias[col] : 0.f;
#pragma unroll
    for (int m = 0; m < 4; ++m) {
      int row = m0 + wm + m * 16 + crow;
#pragma unroll
      for (int q = 0; q < 4; ++q) {
        float v = acc[m][n][q] + bv;
        if (BF16OUT)
          Cb[(size_t)(row + q) * LDC + col] = f2b(v);
        else
          Cf[(size_t)(row + q) * LDC + col] = v;
      }
    }
  }
}

// ---------------- fused bias + relu + per-row mean/var norm (bf16 in) ----------------
__global__ __launch_bounds__(128) void rownorm_b(const u16* __restrict__ F, int ldf,
                                                 const float* __restrict__ bias,
                                                 const float* __restrict__ sc,
                                                 const float* __restrict__ ofs,
                                                 u16* __restrict__ out, int col_off) {
  int r = blockIdx.x, t = threadIdx.x;
  ushort4 uv = *(const ushort4*)(F + (size_t)r * ldf + t * 4);
  float4 b4 = *(const float4*)(bias + t * 4);
  float4 v;
  v.x = fmaxf(b2f(uv.x) + b4.x, 0.f);
  v.y = fmaxf(b2f(uv.y) + b4.y, 0.f);
  v.z = fmaxf(b2f(uv.z) + b4.z, 0.f);
  v.w = fmaxf(b2f(uv.w) + b4.w, 0.f);
  float sum = v.x + v.y + v.z + v.w;
  float sq = v.x * v.x + v.y * v.y + v.z * v.z + v.w * v.w;
  for (int d = 32; d > 0; d >>= 1) {
    sum += __shfl_down(sum, d);
    sq  += __shfl_down(sq, d);
  }
  __shared__ float red[4];
  if ((t & 63) == 0) { red[(t >> 6) * 2] = sum; red[(t >> 6) * 2 + 1] = sq; }
  __syncthreads();
  float S = red[0] + red[2], Q = red[1] + red[3];
  float mean = S * (1.f / 512.f);
  float var = Q * (1.f / 512.f) - mean * mean;
  float rstd = rsqrtf(var + 1e-9f);
  float4 s4 = *(const float4*)(sc + t * 4);
  float4 o4 = *(const float4*)(ofs + t * 4);
  ushort4 o;
  o.x = f2b((v.x - mean) * s4.x * rstd + o4.x);
  o.y = f2b((v.y - mean) * s4.y * rstd + o4.y);
  o.z = f2b((v.z - mean) * s4.z * rstd + o4.z);
  o.w = f2b((v.w - mean) * s4.w * rstd + o4.w);
  *(ushort4*)(out + (size_t)r * 1024 + col_off + t * 4) = o;
}

// ---------------- per-row L2 normalize (in place, bf16 [NSUB,1024]) ----------------
__global__ __launch_bounds__(256) void l2norm(u16* __restrict__ H) {
  int r = blockIdx.x, t = threadIdx.x;
  uint2 u = *(const uint2*)(H + (size_t)r * 1024 + t * 4);
  float f0 = __uint_as_float(u.x << 16);
  float f1 = __uint_as_float(u.x & 0xffff0000u);
  float f2 = __uint_as_float(u.y << 16);
  float f3 = __uint_as_float(u.y & 0xffff0000u);
  float sq = f0 * f0 + f1 * f1 + f2 * f2 + f3 * f3;
  for (int d = 32; d > 0; d >>= 1) sq += __shfl_down(sq, d);
  __shared__ float red[4];
  if ((t & 63) == 0) red[t >> 6] = sq;
  __syncthreads();
  float S = red[0] + red[1] + red[2] + red[3];
  float inv = 1.f / fmaxf(sqrtf(S), 1e-12f);
  uint2 o;
  o.x = (u32)f2b(f0 * inv) | ((u32)f2b(f1 * inv) << 16);
  o.y = (u32)f2b(f2 * inv) | ((u32)f2b(f3 * inv) << 16);
  *(uint2*)(H + (size_t)r * 1024 + t * 4) = o;
}

extern "C" void kernel_launch(void* const* d_in, const int* in_sizes, int n_in,
                              void* d_out, int out_size, void* d_ws, size_t ws_size,
                              hipStream_t stream) {
  (void)in_sizes; (void)n_in; (void)out_size; (void)ws_size;
  const float* feat_full = (const float*)d_in[0];
  const int*   nodes = (const int*)d_in[1];
  const int*   arow = (const int*)d_in[2];
  const int*   acol = (const int*)d_in[3];
  const float* aval = (const float*)d_in[4];
  const float* W1_0 = (const float*)d_in[5];
  const float* W1_1 = (const float*)d_in[6];
  const float* b1_0 = (const float*)d_in[7];
  const float* b1_1 = (const float*)d_in[8];
  const float* s1_0 = (const float*)d_in[9];
  const float* s1_1 = (const float*)d_in[10];
  const float* o1_0 = (const float*)d_in[11];
  const float* o1_1 = (const float*)d_in[12];
  const float* W2_0 = (const float*)d_in[13];
  const float* W2_1 = (const float*)d_in[14];
  const float* b2_0 = (const float*)d_in[15];
  const float* b2_1 = (const float*)d_in[16];
  const float* s2_0 = (const float*)d_in[17];
  const float* s2_1 = (const float*)d_in[18];
  const float* o2_0 = (const float*)d_in[19];
  const float* o2_1 = (const float*)d_in[20];
  const float* Wc = (const float*)d_in[21];
  const float* bc = (const float*)d_in[22];
  float* out = (float*)d_out;

  const size_t MB = (size_t)1 << 20;
  char* p = (char*)d_ws;
  u16* FEAT = (u16*)p;                    // 32 MiB [NSUB,512]
  u16* S1   = (u16*)(p + 32 * MB);        // 32 MiB
  u16* H1   = (u16*)(p + 64 * MB);        // 64 MiB [NSUB,1024]
  u16* H2   = (u16*)(p + 128 * MB);       // 64 MiB
  u16* TMPb = (u16*)(p + 192 * MB);       // 32 MiB [NSUB,512] (layer-1 preact)
  u16* TTL  = (u16*)(p + 192 * MB);       // 64 MiB [NSUB,1024] (layer-2, reuses TMPb)
  u16* W1_0b = (u16*)(p + 256 * MB);
  u16* W1_1b = W1_0b + 512 * 512;
  u16* W2cat = W1_1b + 512 * 512;         // [1024,1024]
  u16* Wcb   = W2cat + 1024 * 1024;
  int* row_off = (int*)(p + 264 * MB);
  int* cnt    = row_off + 33024;
  int* cursor = cnt + NSUB;
  int2* cv    = (int2*)(cursor + NSUB);

  hipMemsetAsync(cnt, 0, NSUB * sizeof(int), stream);

  // weights -> bf16 (W2_0/W2_1 concatenated row-wise into W2cat)
  cvt_bf16<<<(512 * 512 / 4 + 255) / 256, 256, 0, stream>>>(W1_0, W1_0b, 512 * 512 / 4);
  cvt_bf16<<<(512 * 512 / 4 + 255) / 256, 256, 0, stream>>>(W1_1, W1_1b, 512 * 512 / 4);
  cvt_bf16<<<(512 * 1024 / 4 + 255) / 256, 256, 0, stream>>>(W2_0, W2cat, 512 * 1024 / 4);
  cvt_bf16<<<(512 * 1024 / 4 + 255) / 256, 256, 0, stream>>>(W2_1, W2cat + 512 * 1024, 512 * 1024 / 4);
  cvt_bf16<<<(512 * 1024 / 4 + 255) / 256, 256, 0, stream>>>(Wc, Wcb, 512 * 1024 / 4);

  gather_cast<<<NSUB, 128, 0, stream>>>(feat_full, nodes, FEAT);

  // CSR build
  edge_count<<<NNZ_E / 256, 256, 0, stream>>>(arow, cnt);
  scan_rows<<<1, 1024, 0, stream>>>(cnt, row_off, cursor);
  edge_scatter<<<NNZ_E / 256, 256, 0, stream>>>(arow, acol, aval, cursor, cv);

  // ---- layer 1 ----
  spmm512<512, false><<<NSUB / 4, 256, 0, stream>>>(row_off, cv, FEAT, S1, 512,
                                                    nullptr, nullptr, nullptr);
  gemm_bt<512, 512, false, true><<<dim3(4, 256), 256, 0, stream>>>(FEAT, W1_0b, nullptr, nullptr, TMPb);
  rownorm_b<<<NSUB, 128, 0, stream>>>(TMPb, 512, b1_0, s1_0, o1_0, H1, 0);
  gemm_bt<512, 512, false, true><<<dim3(4, 256), 256, 0, stream>>>(S1, W1_1b, nullptr, nullptr, TMPb);
  rownorm_b<<<NSUB, 128, 0, stream>>>(TMPb, 512, b1_1, s1_1, o1_1, H1, 512);

  // ---- layer 2 (merged GEMM; hop1 GEMM-before-SpMM; norm fused into spmm) ----
  gemm_bt<1024, 1024, false, true><<<dim3(8, 256), 256, 0, stream>>>(H1, W2cat, nullptr, nullptr, TTL);
  rownorm_b<<<NSUB, 128, 0, stream>>>(TTL, 1024, b2_0, s2_0, o2_0, H2, 0);
  spmm512<1024, true><<<NSUB / 4, 256, 0, stream>>>(row_off, cv, TTL + 512, H2 + 512, 1024,
                                                    b2_1, s2_1, o2_1);

  // ---- L2 normalize + classifier (N=512 -> gridDim.x MUST be 4) ----
  l2norm<<<NSUB, 256, 0, stream>>>(H2);
  gemm_bt<1024, 512, true, false><<<dim3(4, 256), 256, 0, stream>>>(H2, Wcb, bc, out, nullptr);
}